// Round 7
// baseline (521.747 us; speedup 1.0000x reference)
//
#include <hip/hip_runtime.h>
#include <hip/hip_bf16.h>

namespace {

constexpr int S_DIM = 2048;
constexpr int D_DIM = 128;
constexpr int NH    = 16;
constexpr long long KV_ELEMS = 32LL * S_DIM * D_DIM;     // 8,388,608
constexpr size_t    WS_NEED  = (size_t)(2 * KV_ELEMS) * 2; // Kbf16 + VTbf16

typedef float  f32x16 __attribute__((ext_vector_type(16)));
typedef __bf16 bf16x8 __attribute__((ext_vector_type(8)));

union U4 { unsigned int w[4]; bf16x8 v; };

__device__ __forceinline__ unsigned int pk2(float a, float b) {
  union { __bf16 h[2]; unsigned int u; } x;
  x.h[0] = (__bf16)a; x.h[1] = (__bf16)b;
  return x.u;
}

// ---- P1: K f32 -> bf16, same [bh][j][d] layout ----
__global__ __launch_bounds__(256)
void conv_k(const float* __restrict__ k, unsigned short* __restrict__ kw) {
  const long long i = 8LL * (blockIdx.x * 256 + threadIdx.x);
  float4 a = *(const float4*)(k + i);
  float4 b = *(const float4*)(k + i + 4);
  U4 t;
  t.w[0] = pk2(a.x, a.y); t.w[1] = pk2(a.z, a.w);
  t.w[2] = pk2(b.x, b.y); t.w[3] = pk2(b.z, b.w);
  *(bf16x8*)(kw + i) = t.v;
}

// ---- P2: V f32 [bh][j][d] -> VT bf16 [bh][d][j] (32x32 LDS tiles) ----
__global__ __launch_bounds__(256)
void transp_v(const float* __restrict__ v, unsigned short* __restrict__ vt) {
  __shared__ float lds[32][33];
  const int bid = blockIdx.x;
  const int bh  = bid >> 8;            // 0..31
  const int rem = bid & 255;
  const int j0  = (rem >> 2) * 32;     // 64 j-tiles
  const int d0  = (rem & 3) * 32;      // 4 d-tiles
  const int tid = threadIdx.x;

  {
    const int jl = tid >> 3;           // 0..31
    const int d4 = (tid & 7) * 4;      // 0..28
    float4 x = *(const float4*)(v + ((long long)bh * S_DIM + j0 + jl) * D_DIM + d0 + d4);
    lds[d4 + 0][jl] = x.x; lds[d4 + 1][jl] = x.y;
    lds[d4 + 2][jl] = x.z; lds[d4 + 3][jl] = x.w;
  }
  __syncthreads();
  {
    const int dl = tid >> 3;           // 0..31
    const int j4 = (tid & 7) * 4;      // 0..28
    const unsigned int w0 = pk2(lds[dl][j4 + 0], lds[dl][j4 + 1]);
    const unsigned int w1 = pk2(lds[dl][j4 + 2], lds[dl][j4 + 3]);
    const unsigned long long w = (unsigned long long)w0 | ((unsigned long long)w1 << 32);
    *(unsigned long long*)(vt + ((long long)bh * D_DIM + d0 + dl) * S_DIM + j0 + j4) = w;
  }
}

// ---- main: 2-wave blocks, j-split by parity, LDS-free loop ----
template <bool PRE>
__global__ __launch_bounds__(128, 3)
void retnet_main(const float* __restrict__ qg, const float* __restrict__ kg,
                 const float* __restrict__ vg,
                 const unsigned short* __restrict__ kw,
                 const unsigned short* __restrict__ vtw,
                 float* __restrict__ og) {
  // end-combine buffers only (no LDS in main loop)
  __shared__ float xbuf[2][2][64][20];   // [wave][frag][lane][20-word slot, 16 used]
  __shared__ float rsbuf[2][32];

  const int tid  = threadIdx.x;
  const int wave = tid >> 6;
  const int lane = tid & 63;
  const int l31  = lane & 31;
  const int hi   = lane >> 5;

  const int bid = blockIdx.x;            // 0..2047
  const int g   = 63 - (bid >> 5);       // descending size: big blocks first
  const int bh  = bid & 31;
  const int h   = bh & (NH - 1);

  const float u    = exp2f(-(float)(5 + h));
  const float lng  = log1pf(-u);         // ln(gamma)
  const float lg2g = lng * 1.44269504088896340736f;

  const long long base = (long long)bh * S_DIM * D_DIM;
  const float* qp = qg + base;
  const float* kp = kg + base;
  const float* vp = vg + base;
  float*       op = og + base;

  const int wrow0 = 32 * g;              // both waves share these 32 q-rows
  const int ig    = wrow0 + l31;
  const float qscale = -u / expm1f((float)(ig + 1) * lng);   // 1/L_i

  // Q fragments (B-operand of swapped QK^T)
  bf16x8 qf[8];
  {
    const float* qrow = qp + (long long)ig * D_DIM;
    #pragma unroll
    for (int kk = 0; kk < 8; ++kk) {
      const int d0 = 16 * kk + 8 * hi;
      float4 a = *(const float4*)(qrow + d0);
      float4 b = *(const float4*)(qrow + d0 + 4);
      U4 t;
      t.w[0] = pk2(a.x * qscale, a.y * qscale);
      t.w[1] = pk2(a.z * qscale, a.w * qscale);
      t.w[2] = pk2(b.x * qscale, b.y * qscale);
      t.w[3] = pk2(b.z * qscale, b.w * qscale);
      qf[kk] = t.v;
    }
  }

  // decay constants: gamma^{-jl}, jl = (r&3) + 8*(r>>2) + 4*hi
  const float gi1 = exp2f(-lg2g);
  const float gi8 = exp2f(-8.0f * lg2g);
  const float g4[4] = {1.0f, gi1, gi1 * gi1, gi1 * gi1 * gi1};
  const float g8[4] = {1.0f, gi8, gi8 * gi8, gi8 * gi8 * gi8};
  const float gih = hi ? exp2f(-4.0f * lg2g) : 1.0f;

  f32x16 oacc[4] = {};
  float rowsum = 0.0f;

  const unsigned short* kwb = kw  + (long long)bh * S_DIM * D_DIM;   // [j][d]
  const unsigned short* vtb = vtw + (long long)bh * D_DIM * S_DIM;   // [d][j]

  for (int t = wave; t <= g; t += 2) {
    const int j0 = 32 * t;

    // ---- QK^T (swapped): acc -> S^T[jl][i], i = l31 ----
    f32x16 acc = {};
    if (PRE) {
      const unsigned short* kb = kwb + (long long)(j0 + l31) * D_DIM + 8 * hi;
      #pragma unroll
      for (int kk = 0; kk < 8; ++kk) {
        bf16x8 kf = *(const bf16x8*)(kb + 16 * kk);
        acc = __builtin_amdgcn_mfma_f32_32x32x16_bf16(kf, qf[kk], acc, 0, 0, 0);
      }
    } else {
      const float* kr = kp + (long long)(j0 + l31) * D_DIM + 8 * hi;
      #pragma unroll
      for (int kk = 0; kk < 8; ++kk) {
        float4 a = *(const float4*)(kr + 16 * kk);
        float4 b = *(const float4*)(kr + 16 * kk + 4);
        U4 t;
        t.w[0] = pk2(a.x, a.y); t.w[1] = pk2(a.z, a.w);
        t.w[2] = pk2(b.x, b.y); t.w[3] = pk2(b.z, b.w);
        acc = __builtin_amdgcn_mfma_f32_32x32x16_bf16(t.v, qf[kk], acc, 0, 0, 0);
      }
    }

    // ---- decay + causal mask + rowsum (lane-local: i = l31) ----
    const float bb = exp2f((float)(ig - j0) * lg2g) * gih;   // gamma^{ig-j0-4hi}
    float sv[16];
    if (t == g) {
      #pragma unroll
      for (int r = 0; r < 16; ++r) {
        const int jl = (r & 3) + 8 * (r >> 2) + 4 * hi;
        float s = acc[r] * (bb * g8[r >> 2] * g4[r & 3]);
        s = (l31 >= jl) ? s : 0.0f;
        rowsum += s; sv[r] = s;
      }
    } else {
      #pragma unroll
      for (int r = 0; r < 16; ++r) {
        const float s = acc[r] * (bb * g8[r >> 2] * g4[r & 3]);
        rowsum += s; sv[r] = s;
      }
    }

    // ---- pack S to bf16 + half-wave exchange -> PV A fragments ----
    unsigned int W[4][2], XW[4][2];
    #pragma unroll
    for (int qd = 0; qd < 4; ++qd) {
      W[qd][0] = pk2(sv[4 * qd + 0], sv[4 * qd + 1]);
      W[qd][1] = pk2(sv[4 * qd + 2], sv[4 * qd + 3]);
    }
    #pragma unroll
    for (int qd = 0; qd < 4; ++qd) {
      XW[qd][0] = (unsigned int)__shfl_xor((int)W[qd][0], 32, 64);
      XW[qd][1] = (unsigned int)__shfl_xor((int)W[qd][1], 32, 64);
    }

    #pragma unroll
    for (int jc = 0; jc < 2; ++jc) {
      U4 af;
      if (hi == 0) {
        af.w[0] = W[2 * jc][0];      af.w[1] = W[2 * jc][1];
        af.w[2] = XW[2 * jc][0];     af.w[3] = XW[2 * jc][1];
      } else {
        af.w[0] = XW[2 * jc + 1][0]; af.w[1] = XW[2 * jc + 1][1];
        af.w[2] = W[2 * jc + 1][0];  af.w[3] = W[2 * jc + 1][1];
      }
      if (PRE) {
        // vf = VT[d = 32dc+l31][j0+16jc+8hi + e], e=0..7 -> one b128 per frag
        const unsigned short* vrow = vtb + (long long)l31 * S_DIM + (j0 + 16 * jc + 8 * hi);
        #pragma unroll
        for (int dc = 0; dc < 4; ++dc) {
          bf16x8 vf = *(const bf16x8*)(vrow + (long long)(32 * dc) * S_DIM);
          oacc[dc] = __builtin_amdgcn_mfma_f32_32x32x16_bf16(af.v, vf, oacc[dc], 0, 0, 0);
        }
      } else {
        const float* vbase = vp + (long long)(j0 + 16 * jc + 8 * hi) * D_DIM + l31;
        #pragma unroll
        for (int dc = 0; dc < 4; ++dc) {
          const float* vcol = vbase + 32 * dc;
          float ve[8];
          #pragma unroll
          for (int e = 0; e < 8; ++e) ve[e] = vcol[e * D_DIM];
          U4 vf;
          vf.w[0] = pk2(ve[0], ve[1]); vf.w[1] = pk2(ve[2], ve[3]);
          vf.w[2] = pk2(ve[4], ve[5]); vf.w[3] = pk2(ve[6], ve[7]);
          oacc[dc] = __builtin_amdgcn_mfma_f32_32x32x16_bf16(af.v, vf.v, oacc[dc], 0, 0, 0);
        }
      }
    }
  }

  // ---- cross-wave combine (single barrier) ----
  const int sendf = wave ? 0 : 2;        // wave0 sends oacc[2,3]; wave1 sends oacc[0,1]
  #pragma unroll
  for (int f = 0; f < 2; ++f) {
    const f32x16 src = oacc[sendf + f];
    #pragma unroll
    for (int m = 0; m < 4; ++m) {
      float4 tmp;
      tmp.x = src[4 * m + 0]; tmp.y = src[4 * m + 1];
      tmp.z = src[4 * m + 2]; tmp.w = src[4 * m + 3];
      *(float4*)(&xbuf[wave][f][lane][4 * m]) = tmp;
    }
  }
  const float rtot = rowsum + __shfl_xor(rowsum, 32, 64);
  if (hi == 0) rsbuf[wave][l31] = rtot;
  __syncthreads();

  const int keepf = wave ? 2 : 0;        // wave0 outputs d-cols 0..63; wave1 64..127
  #pragma unroll
  for (int f = 0; f < 2; ++f) {
    #pragma unroll
    for (int m = 0; m < 4; ++m) {
      float4 x = *(const float4*)(&xbuf[wave ^ 1][f][lane][4 * m]);
      oacc[keepf + f][4 * m + 0] += x.x;
      oacc[keepf + f][4 * m + 1] += x.y;
      oacc[keepf + f][4 * m + 2] += x.z;
      oacc[keepf + f][4 * m + 3] += x.w;
    }
  }
  const float tot  = rtot + rsbuf[wave ^ 1][l31];
  const float invp = 1.0f / fmaxf(fabsf(tot), 1.0f);

  #pragma unroll
  for (int r = 0; r < 16; ++r) {
    const int il = (r & 3) + 8 * (r >> 2) + 4 * hi;
    const float pr = __shfl(invp, il, 32);
    float* orow = op + (long long)(wrow0 + il) * D_DIM + l31;
    #pragma unroll
    for (int f = 0; f < 2; ++f) {
      const int dc = keepf + f;
      orow[32 * dc] = oacc[dc][r] * pr;
    }
  }
}

} // namespace

extern "C" void kernel_launch(void* const* d_in, const int* in_sizes, int n_in,
                              void* d_out, int out_size, void* d_ws, size_t ws_size,
                              hipStream_t stream) {
  const float* q = (const float*)d_in[0];
  const float* k = (const float*)d_in[1];
  const float* v = (const float*)d_in[2];
  // d_in[3] (omask) deliberately never read: decay is analytic.
  float* o = (float*)d_out;

  if (ws_size >= WS_NEED) {
    unsigned short* kw = (unsigned short*)d_ws;
    unsigned short* vt = kw + KV_ELEMS;
    conv_k  <<<(int)(KV_ELEMS / 8 / 256), 256, 0, stream>>>(k, kw);
    transp_v<<<32 * 64 * 4,               256, 0, stream>>>(v, vt);
    retnet_main<true ><<<2048, 128, 0, stream>>>(q, k, v, kw, vt, o);
  } else {
    retnet_main<false><<<2048, 128, 0, stream>>>(q, k, v, nullptr, nullptr, o);
  }
}